// Round 1
// 427.783 us; speedup vs baseline: 1.0241x; 1.0241x over previous
//
#include <hip/hip_runtime.h>

#define DIM   1024
#define SEQ   2048
#define NH    16
#define HD    64

typedef __attribute__((ext_vector_type(8))) short frag_ab;
typedef __attribute__((ext_vector_type(4))) float f32x4;

__device__ __forceinline__ ushort f32_bf16_rne(float f) {
  union { float f; unsigned int u; } v; v.f = f;
  unsigned int u = v.u + 0x7FFFu + ((v.u >> 16) & 1u);
  return (ushort)(u >> 16);
}

__device__ __forceinline__ void split_bf16(float f, ushort& h, ushort& l) {
  h = f32_bf16_rne(f);
  union { unsigned int u; float f; } hv; hv.u = ((unsigned int)h) << 16;
  l = f32_bf16_rne(f - hv.f);
}

__device__ __forceinline__ void gl2lds16(const void* g, void* l) {
  __builtin_amdgcn_global_load_lds(
      (const __attribute__((address_space(1))) unsigned int*)g,
      (__attribute__((address_space(3))) unsigned int*)l, 16, 0, 0);
}

#if __has_builtin(__builtin_amdgcn_exp2f)
#define EXP2F(x) __builtin_amdgcn_exp2f(x)
#else
#define EXP2F(x) exp2f(x)
#endif

// ---------------------------------------------------------------------------
// cast_x: fp32 -> bf16, straight copy. 8 elems/thread.
// ---------------------------------------------------------------------------
__global__ __launch_bounds__(256) void cast_x(const float* __restrict__ x,
                                              ushort* __restrict__ xb) {
  int i = (blockIdx.x * 256 + threadIdx.x) * 8;
  float4 a = *(const float4*)(x + i);
  float4 b = *(const float4*)(x + i + 4);
  uint4 o;
  o.x = (unsigned int)f32_bf16_rne(a.x) | ((unsigned int)f32_bf16_rne(a.y) << 16);
  o.y = (unsigned int)f32_bf16_rne(a.z) | ((unsigned int)f32_bf16_rne(a.w) << 16);
  o.z = (unsigned int)f32_bf16_rne(b.x) | ((unsigned int)f32_bf16_rne(b.y) << 16);
  o.w = (unsigned int)f32_bf16_rne(b.z) | ((unsigned int)f32_bf16_rne(b.w) << 16);
  *(uint4*)(xb + i) = o;
}

// ---------------------------------------------------------------------------
// tcast: transpose + cast W [K][N] f32 -> Wt [N][K] bf16 (optionally hi/lo
// split). 64x64 tile per block via LDS.
// ---------------------------------------------------------------------------
template <bool SPLIT>
__global__ __launch_bounds__(256) void tcast(const float* __restrict__ in,
                                             int K, int N,
                                             ushort* __restrict__ outh,
                                             ushort* __restrict__ outl) {
  __shared__ __align__(16) ushort Th[64][72];
  __shared__ __align__(16) ushort Tl[64][72];
  const int kb = blockIdx.y * 64, nb = blockIdx.x * 64;
  const int t = threadIdx.x;
  const int kr = t >> 4, nc = (t & 15) * 4;
#pragma unroll
  for (int j = 0; j < 4; ++j) {
    int k = kr + j * 16;
    float4 v = *(const float4*)&in[(size_t)(kb + k) * N + nb + nc];
    float vv[4] = {v.x, v.y, v.z, v.w};
#pragma unroll
    for (int i = 0; i < 4; ++i) {
      if (SPLIT) {
        ushort h, l; split_bf16(vv[i], h, l);
        Th[nc + i][k] = h; Tl[nc + i][k] = l;
      } else {
        Th[nc + i][k] = f32_bf16_rne(vv[i]);
      }
    }
  }
  __syncthreads();
  const int n = t >> 2, kc = (t & 3) * 16;
  *(uint4*)&outh[(size_t)(nb + n) * K + kb + kc]     = *(const uint4*)&Th[n][kc];
  *(uint4*)&outh[(size_t)(nb + n) * K + kb + kc + 8] = *(const uint4*)&Th[n][kc + 8];
  if (SPLIT) {
    *(uint4*)&outl[(size_t)(nb + n) * K + kb + kc]     = *(const uint4*)&Tl[n][kc];
    *(uint4*)&outl[(size_t)(nb + n) * K + kb + kc + 8] = *(const uint4*)&Tl[n][kc + 8];
  }
}

// ---------------------------------------------------------------------------
// qkv_mfma: C[8192x3072] = Xb @ Wqt^T (+bias), scatter bf16 to Q,K [bh][s][d]
// and Vt [bh][d][s]. m97 structure: 128x128 tile, BK=32, global_load_lds x16.
// MFMA layouts (m89/m91): A lane=(ml,quad) holds A[m=ml][k=quad*8+j];
// B holds B[k=quad*8+j][n=ml]; C/D: row=quad*4+reg, col=ml.
// ---------------------------------------------------------------------------
__global__ __launch_bounds__(256) void qkv_mfma(
    const ushort* __restrict__ Xb, const ushort* __restrict__ Wqt,
    const float* __restrict__ bias,
    ushort* __restrict__ Qw, ushort* __restrict__ Kw, ushort* __restrict__ Vtw) {
  __shared__ __align__(16) ushort As[128 * 32];
  __shared__ __align__(16) ushort Bs[128 * 32];
  const int t = threadIdx.x, wave = t >> 6, lane = t & 63;
  const int ml = lane & 15, quad = lane >> 4;
  const int m0 = blockIdx.y * 128, n0 = blockIdx.x * 128;
  const int wm = (wave & 1) * 64, wn = (wave >> 1) * 64;
  const int srow = lane >> 2, scol = (lane & 3) * 8;
  const int r0 = wave * 16, r1 = (4 + wave) * 16;

  const ushort* Ag = Xb  + (size_t)(m0 + srow) * DIM + scol;
  const ushort* Bg = Wqt + (size_t)(n0 + srow) * DIM + scol;

  f32x4 acc[4][4];
#pragma unroll
  for (int i = 0; i < 4; ++i)
#pragma unroll
    for (int j = 0; j < 4; ++j) acc[i][j] = (f32x4){0.f, 0.f, 0.f, 0.f};

  for (int k0 = 0; k0 < DIM; k0 += 32) {
    __syncthreads();
    gl2lds16(Ag + (size_t)r0 * DIM + k0, &As[r0 * 32]);
    gl2lds16(Ag + (size_t)r1 * DIM + k0, &As[r1 * 32]);
    gl2lds16(Bg + (size_t)r0 * DIM + k0, &Bs[r0 * 32]);
    gl2lds16(Bg + (size_t)r1 * DIM + k0, &Bs[r1 * 32]);
    __syncthreads();
    frag_ab af[4], bfr[4];
#pragma unroll
    for (int im = 0; im < 4; ++im)
      af[im] = *(const frag_ab*)&As[(wm + im * 16 + ml) * 32 + quad * 8];
#pragma unroll
    for (int in_ = 0; in_ < 4; ++in_)
      bfr[in_] = *(const frag_ab*)&Bs[(wn + in_ * 16 + ml) * 32 + quad * 8];
#pragma unroll
    for (int im = 0; im < 4; ++im)
#pragma unroll
      for (int in_ = 0; in_ < 4; ++in_)
        acc[im][in_] = __builtin_amdgcn_mfma_f32_16x16x32_bf16(
            af[im], bfr[in_], acc[im][in_], 0, 0, 0);
  }

  const int t3 = n0 >> 10;                 // 0:Q 1:K 2:V (block-uniform)
  const int b  = m0 >> 11;
  const int s0 = (m0 & (SEQ - 1)) + wm + quad * 4;
#pragma unroll
  for (int in_ = 0; in_ < 4; ++in_) {
    int n = n0 + wn + in_ * 16 + ml;
    int h = (n >> 6) & 15, d = n & 63;
    float bv = bias[n];
    size_t bh = (size_t)(b * NH + h);
    if (t3 == 2) {
#pragma unroll
      for (int im = 0; im < 4; ++im) {
        int s = s0 + im * 16;
        ushort4 v;
        v.x = f32_bf16_rne(acc[im][in_][0] + bv);
        v.y = f32_bf16_rne(acc[im][in_][1] + bv);
        v.z = f32_bf16_rne(acc[im][in_][2] + bv);
        v.w = f32_bf16_rne(acc[im][in_][3] + bv);
        *(ushort4*)&Vtw[(bh * HD + d) * SEQ + s] = v;
      }
    } else {
      ushort* dst = (t3 == 0) ? Qw : Kw;
#pragma unroll
      for (int im = 0; im < 4; ++im)
#pragma unroll
        for (int r = 0; r < 4; ++r)
          dst[(bh * SEQ + s0 + im * 16 + r) * HD + d] =
              f32_bf16_rne(acc[im][in_][r] + bv);
    }
  }
}

// ---------------------------------------------------------------------------
// attn: flash attention, bf16 MFMA, static-max base-2 softmax.
// Round-2 structure: 2-phase double-buffered K/V staging via global_load_lds
// (distinct LDS buffers per phase so alias analysis keeps loads in flight),
// pad-free XOR-swizzled LDS layouts (linear gl2lds dest + inverse-swizzled
// global SOURCE + swizzled reads, rule 21), Q fragments direct from global
// (no Qs LDS), one barrier per K-tile, XCD-aware block swizzle for K/V L2
// residency, raw v_exp_f32, setprio around MFMA clusters.
// LDS layout per 64x64 bf16 tile: 64 rows x 8 words (16B); word w of row r
// stored at physical word r*8 + (w ^ (r&7)).
// Ol ALIASES the Q buffer (each block reads only its own Q rows at start,
// writes only its own O rows at end) -> no __restrict__ on Qw/Ohw/Olw.
// ---------------------------------------------------------------------------
__global__ __launch_bounds__(256) void attn_kernel(
    const ushort* Qw, const ushort* __restrict__ Kw,
    const ushort* __restrict__ Vtw, ushort* Ohw, ushort* Olw) {
  __shared__ __align__(16) ushort KsA[4096], KsB[4096];
  __shared__ __align__(16) ushort VsA[4096], VsB[4096];
  __shared__ __align__(16) ushort PsL[4][1024];

  const int t    = threadIdx.x;
  const int bid  = blockIdx.x;
  const int sbid = (bid & 7) * 256 + (bid >> 3);   // bijective: 2048 = 8*256
  const int bh   = sbid >> 5;
  const int qt   = sbid & 31;
  const int lane = t & 63, wave = t >> 6;
  const int ml   = lane & 15, quad = lane >> 4;
  const int swz  = ml & 7;
  const int lrow = lane >> 3, lw = lane & 7;

  const size_t qbase  = ((size_t)bh * SEQ + qt * 64) * HD;
  const size_t kbase0 = (size_t)bh * SEQ * HD;
  const size_t vbase0 = (size_t)bh * HD * SEQ;

  // Q fragments straight from global (each lane reads only its own row).
  const frag_ab a_q0 =
      *(const frag_ab*)(Qw + qbase + (size_t)(wave * 16 + ml) * HD + quad * 8);
  const frag_ab a_q1 =
      *(const frag_ab*)(Qw + qbase + (size_t)(wave * 16 + ml) * HD + 32 + quad * 8);

  // Per-lane staging sources, pre-swizzled so linear gl2lds dest yields the
  // XOR-swizzled LDS layout. Wave w stages rows w*16 .. w*16+15 of each tile.
  const ushort* kg = Kw  + kbase0 + (size_t)(wave * 16 + lrow) * HD  + (lw ^ lrow) * 8;
  const ushort* vg = Vtw + vbase0 + (size_t)(wave * 16 + lrow) * SEQ + (lw ^ lrow) * 8;

  gl2lds16(kg,           &KsA[wave * 1024]);
  gl2lds16(kg + 8 * HD,  &KsA[wave * 1024 + 512]);
  gl2lds16(vg,           &VsA[wave * 1024]);
  gl2lds16(vg + 8 * SEQ, &VsA[wave * 1024 + 512]);
  __syncthreads();

  f32x4 O[4];
#pragma unroll
  for (int c = 0; c < 4; ++c) O[c] = (f32x4){0.f, 0.f, 0.f, 0.f};
  float lsum[4] = {0.f, 0.f, 0.f, 0.f};
  const float kscale = 0.125f * 1.4426950408889634f;

#define ATTN_STEP(KT, KS_, VS_, KSN, VSN)                                      \
  {                                                                            \
    if ((KT) < 31) {                                                           \
      const ushort* kgn = kg + (size_t)((KT) + 1) * (64 * HD);                 \
      const ushort* vgn = vg + (size_t)((KT) + 1) * 64;                        \
      gl2lds16(kgn,           &KSN[wave * 1024]);                              \
      gl2lds16(kgn + 8 * HD,  &KSN[wave * 1024 + 512]);                        \
      gl2lds16(vgn,           &VSN[wave * 1024]);                              \
      gl2lds16(vgn + 8 * SEQ, &VSN[wave * 1024 + 512]);                        \
    }                                                                          \
    f32x4 sc[4];                                                               \
    __builtin_amdgcn_s_setprio(1);                                             \
    _Pragma("unroll")                                                          \
    for (int c = 0; c < 4; ++c) {                                              \
      sc[c] = (f32x4){0.f, 0.f, 0.f, 0.f};                                     \
      frag_ab bk0 = *(const frag_ab*)&KS_[(c * 16 + ml) * 64 +                 \
                                          ((quad ^ swz) * 8)];                 \
      sc[c] = __builtin_amdgcn_mfma_f32_16x16x32_bf16(a_q0, bk0, sc[c], 0, 0, 0); \
      frag_ab bk1 = *(const frag_ab*)&KS_[(c * 16 + ml) * 64 +                 \
                                          (((4 + quad) ^ swz) * 8)];           \
      sc[c] = __builtin_amdgcn_mfma_f32_16x16x32_bf16(a_q1, bk1, sc[c], 0, 0, 0); \
    }                                                                          \
    __builtin_amdgcn_s_setprio(0);                                             \
    _Pragma("unroll")                                                          \
    for (int c = 0; c < 4; ++c) {                                              \
      _Pragma("unroll")                                                        \
      for (int r = 0; r < 4; ++r) {                                            \
        float p = EXP2F(fmaf(sc[c][r], kscale, -12.0f));                       \
        union { float f; unsigned int u; } pv_; pv_.f = p;                     \
        unsigned int u = pv_.u & 0xffff0000u;                                  \
        union { unsigned int u; float f; } tf_; tf_.u = u;                     \
        lsum[r] += tf_.f;                                                      \
        unsigned int other = (unsigned int)__shfl_xor((int)u, 1, 64);          \
        if (!(ml & 1)) {                                                       \
          int prow = quad * 4 + r;                                             \
          int pword = c * 2 + (ml >> 3);                                       \
          *(unsigned int*)((char*)&PsL[wave][0] + prow * 128 +                 \
                           ((pword ^ (prow & 7)) * 16) + (ml & 7) * 2) =       \
              (u >> 16) | other;                                               \
        }                                                                      \
      }                                                                        \
    }                                                                          \
    _Pragma("unroll")                                                          \
    for (int ks = 0; ks < 2; ++ks) {                                           \
      frag_ab ap = *(const frag_ab*)((const char*)&PsL[wave][0] + ml * 128 +   \
                                     (((ks * 4 + quad) ^ swz) * 16));          \
      __builtin_amdgcn_s_setprio(1);                                           \
      _Pragma("unroll")                                                        \
      for (int c = 0; c < 4; ++c) {                                            \
        frag_ab bv = *(const frag_ab*)&VS_[(c * 16 + ml) * 64 +                \
                                           (((ks * 4 + quad) ^ swz) * 8)];     \
        O[c] = __builtin_amdgcn_mfma_f32_16x16x32_bf16(ap, bv, O[c], 0, 0, 0); \
      }                                                                        \
      __builtin_amdgcn_s_setprio(0);                                           \
    }                                                                          \
    __syncthreads();                                                           \
  }

  for (int kt = 0; kt < 32; kt += 2) {
    ATTN_STEP(kt,     KsA, VsA, KsB, VsB)
    ATTN_STEP(kt + 1, KsB, VsB, KsA, VsA)
  }
#undef ATTN_STEP

#pragma unroll
  for (int r = 0; r < 4; ++r) {
    float s = lsum[r];
    s += __shfl_xor(s, 1, 64);
    s += __shfl_xor(s, 2, 64);
    s += __shfl_xor(s, 4, 64);
    s += __shfl_xor(s, 8, 64);
    lsum[r] = 1.0f / s;
  }

  const int q0 = qt * 64 + wave * 16 + quad * 4;
#pragma unroll
  for (int r = 0; r < 4; ++r) {
    size_t rowbase = ((size_t)bh * SEQ + q0 + r) * HD;
#pragma unroll
    for (int c = 0; c < 4; ++c) {
      float f = O[c][r] * lsum[r];
      ushort h, l; split_bf16(f, h, l);
      Ohw[rowbase + c * 16 + ml] = h;
      Olw[rowbase + c * 16 + ml] = l;
    }
  }
}

// ---------------------------------------------------------------------------
// proj_mfma: out = (Oh+Ol) @ (Wh+Wl)^T + bias, via virtual K=3072 bf16 GEMM
// (Oh*Wh + Ol*Wh + Oh*Wl; Ol*Wl term ~2^-18, dropped). O buffers are in
// Q-layout [bh][s][d] (row stride 64 within a head-column chunk).
// ---------------------------------------------------------------------------
__global__ __launch_bounds__(256) void proj_mfma(
    const ushort* __restrict__ Oh, const ushort* __restrict__ Ol,
    const ushort* __restrict__ Wph, const ushort* __restrict__ Wpl,
    const float* __restrict__ bias, float* __restrict__ out) {
  __shared__ __align__(16) ushort As[128 * 32];
  __shared__ __align__(16) ushort Bs[128 * 32];
  const int t = threadIdx.x, wave = t >> 6, lane = t & 63;
  const int ml = lane & 15, quad = lane >> 4;
  const int m0 = blockIdx.y * 128, n0 = blockIdx.x * 128;
  const int wm = (wave & 1) * 64, wn = (wave >> 1) * 64;
  const int srow = lane >> 2, scol = (lane & 3) * 8;
  const int r0 = wave * 16, r1 = (4 + wave) * 16;
  const int b = m0 >> 11, s0r = m0 & (SEQ - 1);

  f32x4 acc[4][4];
#pragma unroll
  for (int i = 0; i < 4; ++i)
#pragma unroll
    for (int j = 0; j < 4; ++j) acc[i][j] = (f32x4){0.f, 0.f, 0.f, 0.f};

  for (int kt = 0; kt < 96; ++kt) {
    int ph = kt >> 5;
    int kv = (kt & 31) * 32;                 // virtual k in [0,1024)
    const ushort* Asrc = (ph == 1) ? Ol : Oh;
    const ushort* Bsrc = (ph == 2) ? Wpl : Wph;
    int h = kv >> 6, dbase = kv & 63;
    const ushort* Ag = Asrc + (((size_t)(b * NH + h) * SEQ) + s0r + srow) * HD
                            + dbase + scol;
    const ushort* Bg = Bsrc + (size_t)(n0 + srow) * DIM + kv + scol;
    __syncthreads();
    gl2lds16(Ag + (size_t)r0 * HD, &As[r0 * 32]);
    gl2lds16(Ag + (size_t)r1 * HD, &As[r1 * 32]);
    gl2lds16(Bg + (size_t)r0 * DIM, &Bs[r0 * 32]);
    gl2lds16(Bg + (size_t)r1 * DIM, &Bs[r1 * 32]);
    __syncthreads();
    frag_ab af[4], bfr[4];
#pragma unroll
    for (int im = 0; im < 4; ++im)
      af[im] = *(const frag_ab*)&As[(wm + im * 16 + ml) * 32 + quad * 8];
#pragma unroll
    for (int in_ = 0; in_ < 4; ++in_)
      bfr[in_] = *(const frag_ab*)&Bs[(wn + in_ * 16 + ml) * 32 + quad * 8];
#pragma unroll
    for (int im = 0; im < 4; ++im)
#pragma unroll
      for (int in_ = 0; in_ < 4; ++in_)
        acc[im][in_] = __builtin_amdgcn_mfma_f32_16x16x32_bf16(
            af[im], bfr[in_], acc[im][in_], 0, 0, 0);
  }

#pragma unroll
  for (int in_ = 0; in_ < 4; ++in_) {
    int n = n0 + wn + in_ * 16 + ml;
    float bv = bias[n];
#pragma unroll
    for (int im = 0; im < 4; ++im)
#pragma unroll
      for (int r = 0; r < 4; ++r) {
        int m = m0 + wm + im * 16 + quad * 4 + r;
        out[(size_t)m * DIM + n] = acc[im][in_][r] + bv;
      }
  }
}

extern "C" void kernel_launch(void* const* d_in, const int* in_sizes, int n_in,
                              void* d_out, int out_size, void* d_ws, size_t ws_size,
                              hipStream_t stream) {
  const float* x      = (const float*)d_in[0];
  const float* W_qkv  = (const float*)d_in[1];
  const float* b_qkv  = (const float*)d_in[2];
  const float* W_proj = (const float*)d_in[3];
  const float* b_proj = (const float*)d_in[4];
  float* out = (float*)d_out;

  // workspace (77.6 MB peak):
  //  [0,16.78M)      Xb bf16 [8192][1024]       -> reused as Oh (Q-layout)
  //  [16.78,23.07M)  Wqt bf16 [3072][1024]
  //  [23.07,39.85M)  Q  bf16 [bh][s][d]         -> reused as Ol (Q-layout)
  //  [39.85,56.62M)  K  bf16 [bh][s][d]
  //  [56.62,73.40M)  Vt bf16 [bh][d][s]
  //  [73.40,75.50M)  Wph bf16 [1024][1024]
  //  [75.50,77.59M)  Wpl bf16 [1024][1024]
  char* ws = (char*)d_ws;
  ushort* Xb  = (ushort*)(ws);
  ushort* Wqt = (ushort*)(ws + 16777216ull);
  ushort* Qw  = (ushort*)(ws + 23068672ull);
  ushort* Kw  = (ushort*)(ws + 39845888ull);
  ushort* Vtw = (ushort*)(ws + 56623104ull);
  ushort* Wph = (ushort*)(ws + 73400320ull);
  ushort* Wpl = (ushort*)(ws + 75497472ull);
  ushort* Ohw = Xb;   // Xb dead after qkv_mfma
  ushort* Olw = Qw;   // each attn block reads its Q tile before writing its O

  cast_x<<<dim3(4096), 256, 0, stream>>>(x, Xb);
  tcast<false><<<dim3(48, 16), 256, 0, stream>>>(W_qkv, DIM, 3 * DIM, Wqt, nullptr);
  tcast<true><<<dim3(16, 16), 256, 0, stream>>>(W_proj, DIM, DIM, Wph, Wpl);
  qkv_mfma<<<dim3(24, 64), 256, 0, stream>>>(Xb, Wqt, b_qkv, Qw, Kw, Vtw);
  attn_kernel<<<dim3(2048), 256, 0, stream>>>(Qw, Kw, Vtw, Ohw, Olw);
  proj_mfma<<<dim3(8, 64), 256, 0, stream>>>(Ohw, Olw, Wph, Wpl, b_proj, out);
}

// Round 2
// 381.088 us; speedup vs baseline: 1.1495x; 1.1225x over previous
//
#include <hip/hip_runtime.h>

#define DIM   1024
#define SEQ   2048
#define NH    16
#define HD    64

typedef __attribute__((ext_vector_type(8))) short frag_ab;
typedef __attribute__((ext_vector_type(4))) float f32x4;

__device__ __forceinline__ ushort f32_bf16_rne(float f) {
  union { float f; unsigned int u; } v; v.f = f;
  unsigned int u = v.u + 0x7FFFu + ((v.u >> 16) & 1u);
  return (ushort)(u >> 16);
}

__device__ __forceinline__ void split_bf16(float f, ushort& h, ushort& l) {
  h = f32_bf16_rne(f);
  union { unsigned int u; float f; } hv; hv.u = ((unsigned int)h) << 16;
  l = f32_bf16_rne(f - hv.f);
}

__device__ __forceinline__ void gl2lds16(const void* g, void* l) {
  __builtin_amdgcn_global_load_lds(
      (const __attribute__((address_space(1))) unsigned int*)g,
      (__attribute__((address_space(3))) unsigned int*)l, 16, 0, 0);
}

#if __has_builtin(__builtin_amdgcn_exp2f)
#define EXP2F(x) __builtin_amdgcn_exp2f(x)
#else
#define EXP2F(x) exp2f(x)
#endif

// ---------------------------------------------------------------------------
// cast_x: fp32 -> bf16, straight copy. 8 elems/thread.
// ---------------------------------------------------------------------------
__global__ __launch_bounds__(256) void cast_x(const float* __restrict__ x,
                                              ushort* __restrict__ xb) {
  int i = (blockIdx.x * 256 + threadIdx.x) * 8;
  float4 a = *(const float4*)(x + i);
  float4 b = *(const float4*)(x + i + 4);
  uint4 o;
  o.x = (unsigned int)f32_bf16_rne(a.x) | ((unsigned int)f32_bf16_rne(a.y) << 16);
  o.y = (unsigned int)f32_bf16_rne(a.z) | ((unsigned int)f32_bf16_rne(a.w) << 16);
  o.z = (unsigned int)f32_bf16_rne(b.x) | ((unsigned int)f32_bf16_rne(b.y) << 16);
  o.w = (unsigned int)f32_bf16_rne(b.z) | ((unsigned int)f32_bf16_rne(b.w) << 16);
  *(uint4*)(xb + i) = o;
}

// ---------------------------------------------------------------------------
// tcast: transpose + cast W [K][N] f32 -> Wt [N][K] bf16 (optionally hi/lo
// split). 64x64 tile per block via LDS.
// ---------------------------------------------------------------------------
template <bool SPLIT>
__global__ __launch_bounds__(256) void tcast(const float* __restrict__ in,
                                             int K, int N,
                                             ushort* __restrict__ outh,
                                             ushort* __restrict__ outl) {
  __shared__ __align__(16) ushort Th[64][72];
  __shared__ __align__(16) ushort Tl[64][72];
  const int kb = blockIdx.y * 64, nb = blockIdx.x * 64;
  const int t = threadIdx.x;
  const int kr = t >> 4, nc = (t & 15) * 4;
#pragma unroll
  for (int j = 0; j < 4; ++j) {
    int k = kr + j * 16;
    float4 v = *(const float4*)&in[(size_t)(kb + k) * N + nb + nc];
    float vv[4] = {v.x, v.y, v.z, v.w};
#pragma unroll
    for (int i = 0; i < 4; ++i) {
      if (SPLIT) {
        ushort h, l; split_bf16(vv[i], h, l);
        Th[nc + i][k] = h; Tl[nc + i][k] = l;
      } else {
        Th[nc + i][k] = f32_bf16_rne(vv[i]);
      }
    }
  }
  __syncthreads();
  const int n = t >> 2, kc = (t & 3) * 16;
  *(uint4*)&outh[(size_t)(nb + n) * K + kb + kc]     = *(const uint4*)&Th[n][kc];
  *(uint4*)&outh[(size_t)(nb + n) * K + kb + kc + 8] = *(const uint4*)&Th[n][kc + 8];
  if (SPLIT) {
    *(uint4*)&outl[(size_t)(nb + n) * K + kb + kc]     = *(const uint4*)&Tl[n][kc];
    *(uint4*)&outl[(size_t)(nb + n) * K + kb + kc + 8] = *(const uint4*)&Tl[n][kc + 8];
  }
}

// ---------------------------------------------------------------------------
// qkv_mfma: C[8192x3072] = Xb @ Wqt^T (+bias), scatter bf16 to Q,K [bh][s][d]
// and Vt [bh][d][s]. m97 structure: 128x128 tile, BK=32, global_load_lds x16.
// MFMA layouts (m89/m91): A lane=(ml,quad) holds A[m=ml][k=quad*8+j];
// B holds B[k=quad*8+j][n=ml]; C/D: row=quad*4+reg, col=ml.
// ---------------------------------------------------------------------------
__global__ __launch_bounds__(256) void qkv_mfma(
    const ushort* __restrict__ Xb, const ushort* __restrict__ Wqt,
    const float* __restrict__ bias,
    ushort* __restrict__ Qw, ushort* __restrict__ Kw, ushort* __restrict__ Vtw) {
  __shared__ __align__(16) ushort As[128 * 32];
  __shared__ __align__(16) ushort Bs[128 * 32];
  const int t = threadIdx.x, wave = t >> 6, lane = t & 63;
  const int ml = lane & 15, quad = lane >> 4;
  const int m0 = blockIdx.y * 128, n0 = blockIdx.x * 128;
  const int wm = (wave & 1) * 64, wn = (wave >> 1) * 64;
  const int srow = lane >> 2, scol = (lane & 3) * 8;
  const int r0 = wave * 16, r1 = (4 + wave) * 16;

  const ushort* Ag = Xb  + (size_t)(m0 + srow) * DIM + scol;
  const ushort* Bg = Wqt + (size_t)(n0 + srow) * DIM + scol;

  f32x4 acc[4][4];
#pragma unroll
  for (int i = 0; i < 4; ++i)
#pragma unroll
    for (int j = 0; j < 4; ++j) acc[i][j] = (f32x4){0.f, 0.f, 0.f, 0.f};

  for (int k0 = 0; k0 < DIM; k0 += 32) {
    __syncthreads();
    gl2lds16(Ag + (size_t)r0 * DIM + k0, &As[r0 * 32]);
    gl2lds16(Ag + (size_t)r1 * DIM + k0, &As[r1 * 32]);
    gl2lds16(Bg + (size_t)r0 * DIM + k0, &Bs[r0 * 32]);
    gl2lds16(Bg + (size_t)r1 * DIM + k0, &Bs[r1 * 32]);
    __syncthreads();
    frag_ab af[4], bfr[4];
#pragma unroll
    for (int im = 0; im < 4; ++im)
      af[im] = *(const frag_ab*)&As[(wm + im * 16 + ml) * 32 + quad * 8];
#pragma unroll
    for (int in_ = 0; in_ < 4; ++in_)
      bfr[in_] = *(const frag_ab*)&Bs[(wn + in_ * 16 + ml) * 32 + quad * 8];
#pragma unroll
    for (int im = 0; im < 4; ++im)
#pragma unroll
      for (int in_ = 0; in_ < 4; ++in_)
        acc[im][in_] = __builtin_amdgcn_mfma_f32_16x16x32_bf16(
            af[im], bfr[in_], acc[im][in_], 0, 0, 0);
  }

  const int t3 = n0 >> 10;                 // 0:Q 1:K 2:V (block-uniform)
  const int b  = m0 >> 11;
  const int s0 = (m0 & (SEQ - 1)) + wm + quad * 4;
#pragma unroll
  for (int in_ = 0; in_ < 4; ++in_) {
    int n = n0 + wn + in_ * 16 + ml;
    int h = (n >> 6) & 15, d = n & 63;
    float bv = bias[n];
    size_t bh = (size_t)(b * NH + h);
    if (t3 == 2) {
#pragma unroll
      for (int im = 0; im < 4; ++im) {
        int s = s0 + im * 16;
        ushort4 v;
        v.x = f32_bf16_rne(acc[im][in_][0] + bv);
        v.y = f32_bf16_rne(acc[im][in_][1] + bv);
        v.z = f32_bf16_rne(acc[im][in_][2] + bv);
        v.w = f32_bf16_rne(acc[im][in_][3] + bv);
        *(ushort4*)&Vtw[(bh * HD + d) * SEQ + s] = v;
      }
    } else {
      ushort* dst = (t3 == 0) ? Qw : Kw;
#pragma unroll
      for (int im = 0; im < 4; ++im)
#pragma unroll
        for (int r = 0; r < 4; ++r)
          dst[(bh * SEQ + s0 + im * 16 + r) * HD + d] =
              f32_bf16_rne(acc[im][in_][r] + bv);
    }
  }
}

// ---------------------------------------------------------------------------
// attn: flash attention, bf16 MFMA, static-max base-2 softmax.
// Round-3 structure: QBLK=128 via 8 waves (512 threads) -- each wave keeps
// the round-2 16-row code path, but K/V tiles are now amortized over 2x the
// Q rows (half the staging + barriers per FLOP) and the grid halves.
// __launch_bounds__(512,8) caps VGPR at 64 (was 68): HW VGPR quantization
// {64,128,256} (m69) means 68 regs -> 4 waves/SIMD; 64 regs + 48KB LDS ->
// 3 blocks/CU = 24 waves/CU resident (vs ~10) to cover the per-step
// dependency chain. Same swizzled gl2lds double-buffer (rule 21), Q frags
// direct from global, XCD-aware block swizzle, raw v_exp_f32, setprio.
// LDS layout per 64x64 bf16 tile: 64 rows x 8 words (16B); word w of row r
// stored at physical word r*8 + (w ^ (r&7)).
// Ol ALIASES the Q buffer (each block reads only its own Q rows at start,
// writes only its own O rows at end) -> no __restrict__ on Qw/Ohw/Olw.
// ---------------------------------------------------------------------------
__global__ __launch_bounds__(512, 8) void attn_kernel(
    const ushort* Qw, const ushort* __restrict__ Kw,
    const ushort* __restrict__ Vtw, ushort* Ohw, ushort* Olw) {
  __shared__ __align__(16) ushort KsA[4096], KsB[4096];
  __shared__ __align__(16) ushort VsA[4096], VsB[4096];
  __shared__ __align__(16) ushort PsL[8][1024];

  const int t    = threadIdx.x;
  const int bid  = blockIdx.x;
  const int sbid = (bid & 7) * 128 + (bid >> 3);   // bijective: 1024 = 8*128
  const int bh   = sbid >> 4;
  const int qt   = sbid & 15;
  const int lane = t & 63, wave = t >> 6;
  const int ml   = lane & 15, quad = lane >> 4;
  const int swz  = ml & 7;
  const int lrow = lane >> 3, lw = lane & 7;

  const size_t qbase  = ((size_t)bh * SEQ + qt * 128) * HD;
  const size_t kbase0 = (size_t)bh * SEQ * HD;
  const size_t vbase0 = (size_t)bh * HD * SEQ;

  // Q fragments straight from global (each lane reads only its own row).
  const frag_ab a_q0 =
      *(const frag_ab*)(Qw + qbase + (size_t)(wave * 16 + ml) * HD + quad * 8);
  const frag_ab a_q1 =
      *(const frag_ab*)(Qw + qbase + (size_t)(wave * 16 + ml) * HD + 32 + quad * 8);

  // Per-lane staging sources, pre-swizzled so linear gl2lds dest yields the
  // XOR-swizzled LDS layout. Wave w stages rows w*8 .. w*8+7 of each tile
  // (8 waves x 8 rows = full 64-row tile, one gl2lds per wave per array).
  const ushort* kg = Kw  + kbase0 + (size_t)(wave * 8 + lrow) * HD  + (lw ^ lrow) * 8;
  const ushort* vg = Vtw + vbase0 + (size_t)(wave * 8 + lrow) * SEQ + (lw ^ lrow) * 8;

  gl2lds16(kg, &KsA[wave * 512]);
  gl2lds16(vg, &VsA[wave * 512]);
  __syncthreads();

  f32x4 O[4];
#pragma unroll
  for (int c = 0; c < 4; ++c) O[c] = (f32x4){0.f, 0.f, 0.f, 0.f};
  float lsum[4] = {0.f, 0.f, 0.f, 0.f};
  const float kscale = 0.125f * 1.4426950408889634f;

#define ATTN_STEP(KT, KS_, VS_, KSN, VSN)                                      \
  {                                                                            \
    if ((KT) < 31) {                                                           \
      gl2lds16(kg + (size_t)((KT) + 1) * (64 * HD), &KSN[wave * 512]);         \
      gl2lds16(vg + (size_t)((KT) + 1) * 64,        &VSN[wave * 512]);         \
    }                                                                          \
    f32x4 sc[4];                                                               \
    __builtin_amdgcn_s_setprio(1);                                             \
    _Pragma("unroll")                                                          \
    for (int c = 0; c < 4; ++c) {                                              \
      sc[c] = (f32x4){0.f, 0.f, 0.f, 0.f};                                     \
      frag_ab bk0 = *(const frag_ab*)&KS_[(c * 16 + ml) * 64 +                 \
                                          ((quad ^ swz) * 8)];                 \
      sc[c] = __builtin_amdgcn_mfma_f32_16x16x32_bf16(a_q0, bk0, sc[c], 0, 0, 0); \
      frag_ab bk1 = *(const frag_ab*)&KS_[(c * 16 + ml) * 64 +                 \
                                          (((4 + quad) ^ swz) * 8)];           \
      sc[c] = __builtin_amdgcn_mfma_f32_16x16x32_bf16(a_q1, bk1, sc[c], 0, 0, 0); \
    }                                                                          \
    __builtin_amdgcn_s_setprio(0);                                             \
    _Pragma("unroll")                                                          \
    for (int c = 0; c < 4; ++c) {                                              \
      _Pragma("unroll")                                                        \
      for (int r = 0; r < 4; ++r) {                                            \
        float p = EXP2F(fmaf(sc[c][r], kscale, -12.0f));                       \
        union { float f; unsigned int u; } pv_; pv_.f = p;                     \
        unsigned int u = pv_.u & 0xffff0000u;                                  \
        union { unsigned int u; float f; } tf_; tf_.u = u;                     \
        lsum[r] += tf_.f;                                                      \
        unsigned int other = (unsigned int)__shfl_xor((int)u, 1, 64);          \
        if (!(ml & 1)) {                                                       \
          int prow = quad * 4 + r;                                             \
          int pword = c * 2 + (ml >> 3);                                       \
          *(unsigned int*)((char*)&PsL[wave][0] + prow * 128 +                 \
                           ((pword ^ (prow & 7)) * 16) + (ml & 7) * 2) =       \
              (u >> 16) | other;                                               \
        }                                                                      \
      }                                                                        \
    }                                                                          \
    _Pragma("unroll")                                                          \
    for (int ks = 0; ks < 2; ++ks) {                                           \
      frag_ab ap = *(const frag_ab*)((const char*)&PsL[wave][0] + ml * 128 +   \
                                     (((ks * 4 + quad) ^ swz) * 16));          \
      __builtin_amdgcn_s_setprio(1);                                           \
      _Pragma("unroll")                                                        \
      for (int c = 0; c < 4; ++c) {                                            \
        frag_ab bv = *(const frag_ab*)&VS_[(c * 16 + ml) * 64 +                \
                                           (((ks * 4 + quad) ^ swz) * 8)];     \
        O[c] = __builtin_amdgcn_mfma_f32_16x16x32_bf16(ap, bv, O[c], 0, 0, 0); \
      }                                                                        \
      __builtin_amdgcn_s_setprio(0);                                           \
    }                                                                          \
    __syncthreads();                                                           \
  }

  for (int kt = 0; kt < 32; kt += 2) {
    ATTN_STEP(kt,     KsA, VsA, KsB, VsB)
    ATTN_STEP(kt + 1, KsB, VsB, KsA, VsA)
  }
#undef ATTN_STEP

#pragma unroll
  for (int r = 0; r < 4; ++r) {
    float s = lsum[r];
    s += __shfl_xor(s, 1, 64);
    s += __shfl_xor(s, 2, 64);
    s += __shfl_xor(s, 4, 64);
    s += __shfl_xor(s, 8, 64);
    lsum[r] = 1.0f / s;
  }

  const int q0 = qt * 128 + wave * 16 + quad * 4;
#pragma unroll
  for (int r = 0; r < 4; ++r) {
    size_t rowbase = ((size_t)bh * SEQ + q0 + r) * HD;
#pragma unroll
    for (int c = 0; c < 4; ++c) {
      float f = O[c][r] * lsum[r];
      ushort h, l; split_bf16(f, h, l);
      Ohw[rowbase + c * 16 + ml] = h;
      Olw[rowbase + c * 16 + ml] = l;
    }
  }
}

// ---------------------------------------------------------------------------
// proj_mfma: out = (Oh+Ol) @ (Wh+Wl)^T + bias, via virtual K=3072 bf16 GEMM
// (Oh*Wh + Ol*Wh + Oh*Wl; Ol*Wl term ~2^-18, dropped). O buffers are in
// Q-layout [bh][s][d] (row stride 64 within a head-column chunk).
// ---------------------------------------------------------------------------
__global__ __launch_bounds__(256) void proj_mfma(
    const ushort* __restrict__ Oh, const ushort* __restrict__ Ol,
    const ushort* __restrict__ Wph, const ushort* __restrict__ Wpl,
    const float* __restrict__ bias, float* __restrict__ out) {
  __shared__ __align__(16) ushort As[128 * 32];
  __shared__ __align__(16) ushort Bs[128 * 32];
  const int t = threadIdx.x, wave = t >> 6, lane = t & 63;
  const int ml = lane & 15, quad = lane >> 4;
  const int m0 = blockIdx.y * 128, n0 = blockIdx.x * 128;
  const int wm = (wave & 1) * 64, wn = (wave >> 1) * 64;
  const int srow = lane >> 2, scol = (lane & 3) * 8;
  const int r0 = wave * 16, r1 = (4 + wave) * 16;
  const int b = m0 >> 11, s0r = m0 & (SEQ - 1);

  f32x4 acc[4][4];
#pragma unroll
  for (int i = 0; i < 4; ++i)
#pragma unroll
    for (int j = 0; j < 4; ++j) acc[i][j] = (f32x4){0.f, 0.f, 0.f, 0.f};

  for (int kt = 0; kt < 96; ++kt) {
    int ph = kt >> 5;
    int kv = (kt & 31) * 32;                 // virtual k in [0,1024)
    const ushort* Asrc = (ph == 1) ? Ol : Oh;
    const ushort* Bsrc = (ph == 2) ? Wpl : Wph;
    int h = kv >> 6, dbase = kv & 63;
    const ushort* Ag = Asrc + (((size_t)(b * NH + h) * SEQ) + s0r + srow) * HD
                            + dbase + scol;
    const ushort* Bg = Bsrc + (size_t)(n0 + srow) * DIM + kv + scol;
    __syncthreads();
    gl2lds16(Ag + (size_t)r0 * HD, &As[r0 * 32]);
    gl2lds16(Ag + (size_t)r1 * HD, &As[r1 * 32]);
    gl2lds16(Bg + (size_t)r0 * DIM, &Bs[r0 * 32]);
    gl2lds16(Bg + (size_t)r1 * DIM, &Bs[r1 * 32]);
    __syncthreads();
    frag_ab af[4], bfr[4];
#pragma unroll
    for (int im = 0; im < 4; ++im)
      af[im] = *(const frag_ab*)&As[(wm + im * 16 + ml) * 32 + quad * 8];
#pragma unroll
    for (int in_ = 0; in_ < 4; ++in_)
      bfr[in_] = *(const frag_ab*)&Bs[(wn + in_ * 16 + ml) * 32 + quad * 8];
#pragma unroll
    for (int im = 0; im < 4; ++im)
#pragma unroll
      for (int in_ = 0; in_ < 4; ++in_)
        acc[im][in_] = __builtin_amdgcn_mfma_f32_16x16x32_bf16(
            af[im], bfr[in_], acc[im][in_], 0, 0, 0);
  }

#pragma unroll
  for (int in_ = 0; in_ < 4; ++in_) {
    int n = n0 + wn + in_ * 16 + ml;
    float bv = bias[n];
#pragma unroll
    for (int im = 0; im < 4; ++im)
#pragma unroll
      for (int r = 0; r < 4; ++r) {
        int m = m0 + wm + im * 16 + quad * 4 + r;
        out[(size_t)m * DIM + n] = acc[im][in_][r] + bv;
      }
  }
}

extern "C" void kernel_launch(void* const* d_in, const int* in_sizes, int n_in,
                              void* d_out, int out_size, void* d_ws, size_t ws_size,
                              hipStream_t stream) {
  const float* x      = (const float*)d_in[0];
  const float* W_qkv  = (const float*)d_in[1];
  const float* b_qkv  = (const float*)d_in[2];
  const float* W_proj = (const float*)d_in[3];
  const float* b_proj = (const float*)d_in[4];
  float* out = (float*)d_out;

  // workspace (77.6 MB peak):
  //  [0,16.78M)      Xb bf16 [8192][1024]       -> reused as Oh (Q-layout)
  //  [16.78,23.07M)  Wqt bf16 [3072][1024]
  //  [23.07,39.85M)  Q  bf16 [bh][s][d]         -> reused as Ol (Q-layout)
  //  [39.85,56.62M)  K  bf16 [bh][s][d]
  //  [56.62,73.40M)  Vt bf16 [bh][d][s]
  //  [73.40,75.50M)  Wph bf16 [1024][1024]
  //  [75.50,77.59M)  Wpl bf16 [1024][1024]
  char* ws = (char*)d_ws;
  ushort* Xb  = (ushort*)(ws);
  ushort* Wqt = (ushort*)(ws + 16777216ull);
  ushort* Qw  = (ushort*)(ws + 23068672ull);
  ushort* Kw  = (ushort*)(ws + 39845888ull);
  ushort* Vtw = (ushort*)(ws + 56623104ull);
  ushort* Wph = (ushort*)(ws + 73400320ull);
  ushort* Wpl = (ushort*)(ws + 75497472ull);
  ushort* Ohw = Xb;   // Xb dead after qkv_mfma
  ushort* Olw = Qw;   // each attn block reads its Q tile before writing its O

  cast_x<<<dim3(4096), 256, 0, stream>>>(x, Xb);
  tcast<false><<<dim3(48, 16), 256, 0, stream>>>(W_qkv, DIM, 3 * DIM, Wqt, nullptr);
  tcast<true><<<dim3(16, 16), 256, 0, stream>>>(W_proj, DIM, DIM, Wph, Wpl);
  qkv_mfma<<<dim3(24, 64), 256, 0, stream>>>(Xb, Wqt, b_qkv, Qw, Kw, Vtw);
  attn_kernel<<<dim3(1024), 512, 0, stream>>>(Qw, Kw, Vtw, Ohw, Olw);
  proj_mfma<<<dim3(8, 64), 256, 0, stream>>>(Ohw, Olw, Wph, Wpl, b_proj, out);
}